// Round 18
// baseline (130.521 us; speedup 1.0000x reference)
//
#include <hip/hip_runtime.h>

// GQA layer, bf16 MFMA pipeline v14 (v13 + BN=96 QKV GEMM tile).
//   cvt5: x,wq,wk,wv -> bf16 + bias concat;
//   QKV GEMM 128x96 tile (BK=64 dual-panel, Q pre-scaled 0.125*log2e; V-col
//   frags write Vt transposed; trailing blocks convert wo->bf16, overlapped);
//   attn: split-K parity waves, pair-staged dbuf LDS (XOR-swizzled src),
//         permlane32_swap exchanges, LSE merge in aliased LDS;
//   out = Ob@wo^T+bo (128x64 GEMM).

#define S_LEN 2048
#define DM    2048
#define QKVW  3072   // Q|K|V row width

typedef float  f32x4  __attribute__((ext_vector_type(4)));
typedef float  f32x16 __attribute__((ext_vector_type(16)));
typedef __bf16 bf16x8 __attribute__((ext_vector_type(8)));
typedef unsigned short u16;
typedef unsigned int   u32;
typedef u16 u16x8 __attribute__((ext_vector_type(8)));
typedef u16 u16x4 __attribute__((ext_vector_type(4)));
typedef u32 u32x4 __attribute__((ext_vector_type(4)));
typedef u32 u32x2 __attribute__((ext_vector_type(2)));

__device__ __forceinline__ u16 f2b(float f) {
    __bf16 h = (__bf16)f;
    return __builtin_bit_cast(unsigned short, h);
}
__device__ __forceinline__ u32 pk2(float lo, float hi) {
    return (u32)f2b(lo) | ((u32)f2b(hi) << 16);
}
__device__ __forceinline__ float max3f(float a, float b, float c) {
    return fmaxf(fmaxf(a, b), c);   // fuses to v_max3_f32
}

// Cross-half exchange: (lo, hi) = ([a.lo|b.lo], [a.hi|b.hi]) across the
// lane<32 / lane>=32 split. T12 primitive (m214v22/m255).
__device__ __forceinline__ void xswap(u32 a, u32 b, u32& lo, u32& hi) {
#if __has_builtin(__builtin_amdgcn_permlane32_swap)
    u32x2 r = __builtin_amdgcn_permlane32_swap(a, b, false, false);
    lo = r[0]; hi = r[1];
#else
    const int hf = (threadIdx.x & 63) >> 5;
    const u32 sA = __shfl_xor(a, 32), sB = __shfl_xor(b, 32);
    lo = hf ? sB : a;
    hi = hf ? b : sA;
#endif
}
__device__ __forceinline__ float xhalf_max(float x) {
    u32 xb = __builtin_bit_cast(u32, x), lo, hi;
    xswap(xb, xb, lo, hi);
    return fmaxf(__builtin_bit_cast(float, lo), __builtin_bit_cast(float, hi));
}
__device__ __forceinline__ float xhalf_sum(float x) {
    u32 xb = __builtin_bit_cast(u32, x), lo, hi;
    xswap(xb, xb, lo, hi);
    return __builtin_bit_cast(float, lo) + __builtin_bit_cast(float, hi);
}

#define MFMA16(a, b, c) __builtin_amdgcn_mfma_f32_16x16x32_bf16((a), (b), (c), 0, 0, 0)
#define MFMA32(a, b, c) __builtin_amdgcn_mfma_f32_32x32x16_bf16((a), (b), (c), 0, 0, 0)

__device__ __forceinline__ void gld16(const void* g, void* l) {
    __builtin_amdgcn_global_load_lds(
        (const __attribute__((address_space(1))) void*)g,
        (__attribute__((address_space(3))) void*)l, 16, 0, 0);
}

// ---------------------------------------------------------------------------
// cvt5: x, wq, wk, wv -> bf16 (x8 groups) + bias concat.
// ---------------------------------------------------------------------------
__global__ __launch_bounds__(256) void cvt5(
    const float* __restrict__ x,  const float* __restrict__ wq,
    const float* __restrict__ wk, const float* __restrict__ wv,
    const float* __restrict__ bq, const float* __restrict__ bk,
    const float* __restrict__ bv,
    u16* __restrict__ xb, u16* __restrict__ wqkvb,
    float* __restrict__ bqkv)
{
    if (blockIdx.x == 5120) {
        for (int i = threadIdx.x; i < 3072; i += 256)
            bqkv[i] = (i < 2048) ? bq[i] : (i < 2560 ? bk[i - 2048] : bv[i - 2560]);
        return;
    }
    int i = blockIdx.x * 256 + threadIdx.x;
    const float* s; u16* d; int off;
    if      (i < 524288)  { s = x;  d = xb;    off = i; }
    else if (i < 1048576) { s = wq; d = wqkvb; off = i - 524288; }
    else if (i < 1179648) { s = wk; d = wqkvb + (size_t)2048 * 2048; off = i - 1048576; }
    else                  { s = wv; d = wqkvb + (size_t)2560 * 2048; off = i - 1179648; }
    const float4* s4 = (const float4*)s;
    float4 a = s4[2 * (size_t)off], b = s4[2 * (size_t)off + 1];
    u16x8 o;
    o[0] = f2b(a.x); o[1] = f2b(a.y); o[2] = f2b(a.z); o[3] = f2b(a.w);
    o[4] = f2b(b.x); o[5] = f2b(b.y); o[6] = f2b(b.z); o[7] = f2b(b.w);
    ((u16x8*)d)[(size_t)off] = o;
}

// ---------------------------------------------------------------------------
// NT GEMM, bf16 in / fp32 acc. 128xBN tile (BN = 96 or 64), BK=64 as two
// BK=32 panels. 4 waves (2x2); wave tile 64 x BN/2 = 4 x (BN/32) 16x16 frags.
// VFUSE: frags with colbase >= 2560 (V cols) write Vt transposed; blocks with
// bid >= ngemm convert wo->bf16 (overlapped).
// ---------------------------------------------------------------------------
template <int BN, bool OUT_BF16, bool QSCALE, bool VFUSE>
__global__ __launch_bounds__(256) void gemm_nt64(
    const u16* __restrict__ A, const u16* __restrict__ B,
    const float* __restrict__ bias, void* __restrict__ Cv,
    u16* __restrict__ Vt,
    const float* __restrict__ wosrc, u16* __restrict__ wodst,
    int N, int K, int nxb, int ngemm)
{
    constexpr int NF   = BN / 32;      // n-frags per wave (3 or 2)
    constexpr int WCOL = BN / 2;       // wave col span
    constexpr int CB   = BN * 4;       // B cells (16B) per panel

    __shared__ u16 As[2][128 * 32];
    __shared__ u16 Bs[2][BN * 32];
    const int bid = blockIdx.x;

    if (VFUSE && bid >= ngemm) {        // trailing wo-conversion blocks
        const int i = (bid - ngemm) * 256 + threadIdx.x;   // 0..524287
        const float4* s4 = (const float4*)wosrc;
        float4 a = s4[2 * (size_t)i], b = s4[2 * (size_t)i + 1];
        u16x8 o;
        o[0] = f2b(a.x); o[1] = f2b(a.y); o[2] = f2b(a.z); o[3] = f2b(a.w);
        o[4] = f2b(b.x); o[5] = f2b(b.y); o[6] = f2b(b.z); o[7] = f2b(b.w);
        ((u16x8*)wodst)[(size_t)i] = o;
        return;
    }

    const int wg  = (bid & 7) * (ngemm >> 3) + (bid >> 3);
    const int bm  = (wg / nxb) * 128;
    const int bn  = (wg % nxb) * BN;

    const int tid  = threadIdx.x;
    const int lane = tid & 63;
    const int w    = tid >> 6;
    const int wr   = w >> 1, wc = w & 1;
    const int la = lane & 15, lg = lane >> 4;

    f32x4 acc[4][NF] = {};

    char* const abase = (char*)&As[0][0] + w * 1024;
    char* const bbase = (char*)&Bs[0][0] + w * 1024;

    for (int k0 = 0; k0 < K; k0 += 64) {
        #pragma unroll
        for (int i = 0; i < 4; ++i) {
            const int c   = tid + 256 * i;
            const int kh  = c >> 9;
            const int rem = c & 511;
            const int row = rem >> 2;
            const int seg = rem & 3;
            gld16(A + (size_t)(bm + row) * K + k0 + kh * 32 + seg * 8,
                  abase + i * 4096);
        }
        #pragma unroll
        for (int i = 0; i < NF; ++i) {     // 2*CB cells = 256*NF
            const int c   = tid + 256 * i;
            const int kh  = (c >= CB) ? 1 : 0;
            const int rem = c - kh * CB;
            const int row = rem >> 2;
            const int seg = rem & 3;
            gld16(B + (size_t)(bn + row) * K + k0 + kh * 32 + seg * 8,
                  bbase + i * 4096);
        }
        __syncthreads();
        #pragma unroll
        for (int kh = 0; kh < 2; ++kh) {
            bf16x8 af[4], bf[NF];
            #pragma unroll
            for (int m = 0; m < 4; ++m)
                af[m] = *(const bf16x8*)(&As[kh][0] + (wr * 64 + m * 16 + la) * 32 + lg * 8);
            #pragma unroll
            for (int n = 0; n < NF; ++n)
                bf[n] = *(const bf16x8*)(&Bs[kh][0] + (wc * WCOL + n * 16 + la) * 32 + lg * 8);
            #pragma unroll
            for (int m = 0; m < 4; ++m)
                #pragma unroll
                for (int n = 0; n < NF; ++n)
                    acc[m][n] = MFMA16(af[m], bf[n], acc[m][n]);
        }
        __syncthreads();
    }

    #pragma unroll
    for (int m = 0; m < 4; ++m) {
        #pragma unroll
        for (int n = 0; n < NF; ++n) {
            const int colbase = bn + wc * WCOL + n * 16;   // 16-aligned frag
            const int col = colbase + la;
            const float bb = bias[col];
            if (VFUSE && colbase >= 2560) {
                // V columns: write transposed into Vt only.
                u16x4 pk;
                #pragma unroll
                for (int j = 0; j < 4; ++j)
                    pk[j] = f2b(acc[m][n][j] + bb);
                const int row0 = bm + wr * 64 + m * 16 + lg * 4;
                *(u16x4*)&Vt[(size_t)(col - 2560) * S_LEN + row0] = pk;
            } else {
                const float osc = (QSCALE && col < 2048) ? 0.180336881f : 1.0f;
                #pragma unroll
                for (int j = 0; j < 4; ++j) {
                    const int row = bm + wr * 64 + m * 16 + lg * 4 + j;
                    const float v = (acc[m][n][j] + bb) * osc;
                    if (OUT_BF16) ((u16*)Cv)[(size_t)row * N + col] = f2b(v);
                    else          ((float*)Cv)[(size_t)row * N + col] = v;
                }
            }
        }
    }
}

// ---------------------------------------------------------------------------
// Flash attention v14 (= v13). Block = (32-row band, kv-head), 8 waves =
// 4 q-heads x 2 key-parities. Chunk pairs staged into dbuf LDS (XOR-swizzled
// source); K staged in-place from QKVb, V from Vt. permlane32_swap exchanges.
// LSE merge via aliased LDS. Complementary block pairing.
// ---------------------------------------------------------------------------
__global__ __launch_bounds__(512, 4) void attn(
    const u16* __restrict__ QKVb, // [2048][3072], Q cols pre-scaled
    const u16* __restrict__ Vt,   // [8][64][2048]
    u16* __restrict__ Ob)         // [2048][2048] bf16
{
    const int tid  = threadIdx.x;
    const int lane = tid & 63;
    const int w    = tid >> 6;           // 0..7
    const int head = w & 3;
    const int par  = w >> 2;             // key parity
    const int bid  = blockIdx.x;
    const int band = (bid < 256) ? (63 - (bid >> 3)) : ((bid - 256) >> 3);
    const int h    = bid & 7;
    const int hq   = h * 4 + head;
    const int q0   = band * 32;
    const int lq   = lane & 31;
    const int hi   = lane >> 5;

    __shared__ char LDS[65536];

    bf16x8 qf[4];
    #pragma unroll
    for (int ds = 0; ds < 4; ++ds)
        qf[ds] = *(const bf16x8*)&QKVb[(size_t)(q0 + lq) * QKVW + hq * 64 + ds * 16 + hi * 8];

    f32x16 ot[2] = {};
    float m = -3e38f, lsum = 0.f;

    const char* Khb = (const char*)QKVb + 4096 + h * 128;
    const char* Vhb = (const char*)(Vt + (size_t)h * 64 * S_LEN);

    const int r0 = tid >> 3;
    const int s0 = (((tid & 7) ^ (r0 & 7)) << 4);
    const int woff = w * 1024;

    const int nch = (band >> 1) + 1;
    const int nit = (nch + 1) >> 1;

    auto stage_pair = [&](int j) {
        const int pb = (j & 1) * 16384;
        const size_t kr = (size_t)(j * 128 + r0);
        gld16(Khb + kr * 6144 + s0,          LDS + pb + woff);
        gld16(Khb + (kr + 64) * 6144 + s0,   LDS + pb + 8192 + woff);
        const size_t vb = ((size_t)r0 << 12) + (size_t)(j * 256) + s0;
        gld16(Vhb + vb,        LDS + 32768 + pb + woff);
        gld16(Vhb + vb + 128,  LDS + 32768 + pb + 8192 + woff);
    };

    stage_pair(0);
    __syncthreads();

    for (int i = 0; i < nit; ++i) {
        if (i + 1 < nit) stage_pair(i + 1);

        const int cg = 2 * i + par;
        if (cg < nch) {
            const int base = (i & 1) * 16384 + par * 8192;
            const char* Kb = LDS + base;
            const char* Vb = LDS + 32768 + base;
            const int k0 = cg * 64;

            // ---- QK^T (swapped): S^T[key][q], exp2 domain
            f32x16 s[2];
            __builtin_amdgcn_s_setprio(1);
            #pragma unroll
            for (int kt = 0; kt < 2; ++kt) {
                f32x16 acc = {};
                #pragma unroll
                for (int ds = 0; ds < 4; ++ds) {
                    const int key = kt * 32 + lq;
                    const int byteK = (key << 7) + ((ds * 32 + hi * 16) ^ ((key & 7) << 4));
                    bf16x8 kf = *(const bf16x8*)(Kb + byteK);
                    acc = MFMA32(kf, qf[ds], acc);
                }
                s[kt] = acc;
            }
            __builtin_amdgcn_s_setprio(0);

            if (k0 + 63 > q0) {
                #pragma unroll
                for (int kt = 0; kt < 2; ++kt)
                    #pragma unroll
                    for (int r = 0; r < 16; ++r) {
                        const int key = k0 + kt * 32 + (r & 3) + 8 * (r >> 2) + 4 * hi;
                        if (key > q0 + lq) s[kt][r] = -1e30f;
                    }
            }

            // ---- chunk max: v_max3 tree + permlane cross-half
            float t10[11];
            #pragma unroll
            for (int r = 0; r < 10; ++r)
                t10[r] = max3f(s[(3*r) >> 4][(3*r) & 15],
                               s[(3*r+1) >> 4][(3*r+1) & 15],
                               s[(3*r+2) >> 4][(3*r+2) & 15]);
            t10[10] = fmaxf(s[1][14], s[1][15]);
            const float x0 = max3f(t10[0], t10[1], t10[2]);
            const float x1 = max3f(t10[3], t10[4], t10[5]);
            const float x2 = max3f(t10[6], t10[7], t10[8]);
            const float x3 = fmaxf(t10[9], t10[10]);
            const float pm = xhalf_max(fmaxf(max3f(x0, x1, x2), x3));

            // ---- defer-max rescale (exp2 domain, THR = 8*log2e)
            if (!__all(pm <= m + 11.5f)) {
                const float mn   = fmaxf(m, pm);
                const float corr = __builtin_exp2f(m - mn);
                m = mn;
                lsum *= corr;
                #pragma unroll
                for (int r = 0; r < 16; ++r) {
                    const int row = (r & 3) + 8 * (r >> 2) + 4 * hi;
                    const float cr = __shfl(corr, row);
                    ot[0][r] *= cr;
                    ot[1][r] *= cr;
                }
            }

            // ---- P = exp2(S - m); row sum via depth-5 tree
            #pragma unroll
            for (int kt = 0; kt < 2; ++kt)
                #pragma unroll
                for (int r = 0; r < 16; ++r)
                    s[kt][r] = __builtin_exp2f(s[kt][r] - m);
            float tsum[16];
            #pragma unroll
            for (int r = 0; r < 16; ++r) tsum[r] = s[0][r] + s[1][r];
            #pragma unroll
            for (int st = 8; st >= 1; st >>= 1)
                #pragma unroll
                for (int r = 0; r < 8; ++r)
                    if (r < st) tsum[r] += tsum[r + st];
            lsum += xhalf_sum(tsum[0]);

            // ---- pack P -> 4 PV A-frags (2 permlane swaps per kb)
            bf16x8 pa[4];
            #pragma unroll
            for (int kb = 0; kb < 4; ++kb) {
                const int kt = kb >> 1;
                const int rb = (kb & 1) * 8;
                const u32 A = pk2(s[kt][rb + 0], s[kt][rb + 1]);
                const u32 B = pk2(s[kt][rb + 4], s[kt][rb + 5]);
                const u32 C = pk2(s[kt][rb + 2], s[kt][rb + 3]);
                const u32 D = pk2(s[kt][rb + 6], s[kt][rb + 7]);
                u32 e0, e1, e2, e3;
                xswap(A, B, e0, e2);
                xswap(C, D, e1, e3);
                u32x4 t4;
                t4[0] = e0; t4[1] = e1; t4[2] = e2; t4[3] = e3;
                pa[kb] = __builtin_bit_cast(bf16x8, t4);
            }

            // ---- PV: U += P @ V
            __builtin_amdgcn_s_setprio(1);
            #pragma unroll
            for (int dt = 0; dt < 2; ++dt)
                #pragma unroll
                for (int kb = 0; kb < 4; ++kb) {
                    const int d = dt * 32 + lq;
                    const int byteV = (d << 7) + ((kb * 32 + hi * 16) ^ ((d & 7) << 4));
                    bf16x8 vf = *(const bf16x8*)(Vb + byteV);
                    ot[dt] = MFMA32(pa[kb], vf, ot[dt]);
                }
            __builtin_amdgcn_s_setprio(0);
        }

        __syncthreads();
    }

    // ---- split-K LSE merge via aliased LDS
    float* Uls = (float*)LDS;                    // [4][32][64]
    float* Mls = (float*)(LDS + 32768);          // [4][32]
    float* Lls = (float*)(LDS + 33280);          // [4][32]

    if (par == 1) {
        #pragma unroll
        for (int r = 0; r < 16; ++r) {
            const int row = (r & 3) + 8 * (r >> 2) + 4 * hi;
            Uls[(head * 32 + row) * 64 + lq]      = ot[0][r];
            Uls[(head * 32 + row) * 64 + 32 + lq] = ot[1][r];
        }
        if (lane < 32) { Mls[head * 32 + lane] = m; Lls[head * 32 + lane] = lsum; }
    }
    __syncthreads();
    if (par == 1) return;

    const float m1  = Mls[head * 32 + lq];
    const float l1  = Lls[head * 32 + lq];
    const float M   = fmaxf(m, m1);
    const float a0  = __builtin_exp2f(m - M);
    const float a1  = __builtin_exp2f(m1 - M);
    const float inv = 1.f / (a0 * lsum + a1 * l1);

    #pragma unroll
    for (int r = 0; r < 16; ++r) {
        const int row = (r & 3) + 8 * (r >> 2) + 4 * hi;
        const float a0r = __shfl(a0, row);
        const float a1r = __shfl(a1, row);
        const float ivr = __shfl(inv, row);
        #pragma unroll
        for (int dt = 0; dt < 2; ++dt) {
            const float u1 = Uls[(head * 32 + row) * 64 + dt * 32 + lq];
            Ob[(size_t)(q0 + row) * DM + hq * 64 + dt * 32 + lq] =
                f2b((a0r * ot[dt][r] + a1r * u1) * ivr);
        }
    }
}

// ---------------------------------------------------------------------------
extern "C" void kernel_launch(void* const* d_in, const int* in_sizes, int n_in,
                              void* d_out, int out_size, void* d_ws, size_t ws_size,
                              hipStream_t stream)
{
    const float* x  = (const float*)d_in[0];
    const float* wq = (const float*)d_in[1];
    const float* bq = (const float*)d_in[2];
    const float* wk = (const float*)d_in[3];
    const float* bk = (const float*)d_in[4];
    const float* wv = (const float*)d_in[5];
    const float* bv = (const float*)d_in[6];
    const float* wo = (const float*)d_in[7];
    const float* bo = (const float*)d_in[8];
    float* out = (float*)d_out;

    char* ws = (char*)d_ws;
    u16* xb     = (u16*)(ws);                  // 8 MB; dead after QKV GEMM
    u16* wqkvb  = (u16*)(ws + (8u  << 20));    // 12 MB; dead after QKV GEMM
    u16* wob    = (u16*)(ws + (20u << 20));    // 8 MB
    u16* QKVb   = (u16*)(ws + (28u << 20));    // 12 MB
    float* bqkv = (float*)(ws + (40u << 20));  // 12 KB
    u16* Ob = xb;                              // 8 MB (aliases dead xb)
    u16* Vt = (u16*)(ws + (41u << 20));        // 2 MB

    cvt5<<<5121, 256, 0, stream>>>(x, wq, wk, wv, bq, bk, bv, xb, wqkvb, bqkv);
    // 512 GEMM blocks (128x96 tiles) + 2048 trailing wo-cvt blocks
    gemm_nt64<96, true, true, true><<<512 + 2048, 256, 0, stream>>>(
        xb, wqkvb, bqkv, QKVb, Vt, wo, wob, QKVW, 2048, QKVW / 96, 512);
    attn<<<512, 512, 0, stream>>>(QKVb, Vt, Ob);
    gemm_nt64<64, false, false, false><<<512, 256, 0, stream>>>(
        Ob, wob, bo, out, nullptr, nullptr, nullptr, DM, 2048, DM / 64, 512);
}

// Round 19
// 127.837 us; speedup vs baseline: 1.0210x; 1.0210x over previous
//
#include <hip/hip_runtime.h>

// GQA layer, bf16 MFMA pipeline v15 (= v13, the 127.9 us config; BN=96 reverted).
//   cvt5: x,wq,wk,wv -> bf16 + bias concat;
//   QKV GEMM 128x64 tile (BK=64 dual-panel, Q pre-scaled 0.125*log2e; V-col
//   blocks write Vt transposed; trailing blocks convert wo->bf16, overlapped);
//   attn: split-K parity waves, pair-staged dbuf LDS (XOR-swizzled src),
//         permlane32_swap exchanges, tree-summed softmax, LSE merge;
//   out = Ob@wo^T+bo (128x64 GEMM).

#define S_LEN 2048
#define DM    2048
#define QKVW  3072   // Q|K|V row width

typedef float  f32x4  __attribute__((ext_vector_type(4)));
typedef float  f32x16 __attribute__((ext_vector_type(16)));
typedef __bf16 bf16x8 __attribute__((ext_vector_type(8)));
typedef unsigned short u16;
typedef unsigned int   u32;
typedef u16 u16x8 __attribute__((ext_vector_type(8)));
typedef u16 u16x4 __attribute__((ext_vector_type(4)));
typedef u32 u32x4 __attribute__((ext_vector_type(4)));
typedef u32 u32x2 __attribute__((ext_vector_type(2)));

__device__ __forceinline__ u16 f2b(float f) {
    __bf16 h = (__bf16)f;
    return __builtin_bit_cast(unsigned short, h);
}
__device__ __forceinline__ u32 pk2(float lo, float hi) {
    return (u32)f2b(lo) | ((u32)f2b(hi) << 16);
}
__device__ __forceinline__ float max3f(float a, float b, float c) {
    return fmaxf(fmaxf(a, b), c);   // fuses to v_max3_f32
}

// Cross-half exchange: (lo, hi) = ([a.lo|b.lo], [a.hi|b.hi]) across the
// lane<32 / lane>=32 split. T12 primitive (m214v22/m255).
__device__ __forceinline__ void xswap(u32 a, u32 b, u32& lo, u32& hi) {
#if __has_builtin(__builtin_amdgcn_permlane32_swap)
    u32x2 r = __builtin_amdgcn_permlane32_swap(a, b, false, false);
    lo = r[0]; hi = r[1];
#else
    const int hf = (threadIdx.x & 63) >> 5;
    const u32 sA = __shfl_xor(a, 32), sB = __shfl_xor(b, 32);
    lo = hf ? sB : a;
    hi = hf ? b : sA;
#endif
}
__device__ __forceinline__ float xhalf_max(float x) {
    u32 xb = __builtin_bit_cast(u32, x), lo, hi;
    xswap(xb, xb, lo, hi);
    return fmaxf(__builtin_bit_cast(float, lo), __builtin_bit_cast(float, hi));
}
__device__ __forceinline__ float xhalf_sum(float x) {
    u32 xb = __builtin_bit_cast(u32, x), lo, hi;
    xswap(xb, xb, lo, hi);
    return __builtin_bit_cast(float, lo) + __builtin_bit_cast(float, hi);
}

#define MFMA16(a, b, c) __builtin_amdgcn_mfma_f32_16x16x32_bf16((a), (b), (c), 0, 0, 0)
#define MFMA32(a, b, c) __builtin_amdgcn_mfma_f32_32x32x16_bf16((a), (b), (c), 0, 0, 0)

__device__ __forceinline__ void gld16(const void* g, void* l) {
    __builtin_amdgcn_global_load_lds(
        (const __attribute__((address_space(1))) void*)g,
        (__attribute__((address_space(3))) void*)l, 16, 0, 0);
}

// ---------------------------------------------------------------------------
// cvt5: x, wq, wk, wv -> bf16 (x8 groups) + bias concat.
// ---------------------------------------------------------------------------
__global__ __launch_bounds__(256) void cvt5(
    const float* __restrict__ x,  const float* __restrict__ wq,
    const float* __restrict__ wk, const float* __restrict__ wv,
    const float* __restrict__ bq, const float* __restrict__ bk,
    const float* __restrict__ bv,
    u16* __restrict__ xb, u16* __restrict__ wqkvb,
    float* __restrict__ bqkv)
{
    if (blockIdx.x == 5120) {
        for (int i = threadIdx.x; i < 3072; i += 256)
            bqkv[i] = (i < 2048) ? bq[i] : (i < 2560 ? bk[i - 2048] : bv[i - 2560]);
        return;
    }
    int i = blockIdx.x * 256 + threadIdx.x;
    const float* s; u16* d; int off;
    if      (i < 524288)  { s = x;  d = xb;    off = i; }
    else if (i < 1048576) { s = wq; d = wqkvb; off = i - 524288; }
    else if (i < 1179648) { s = wk; d = wqkvb + (size_t)2048 * 2048; off = i - 1048576; }
    else                  { s = wv; d = wqkvb + (size_t)2560 * 2048; off = i - 1179648; }
    const float4* s4 = (const float4*)s;
    float4 a = s4[2 * (size_t)off], b = s4[2 * (size_t)off + 1];
    u16x8 o;
    o[0] = f2b(a.x); o[1] = f2b(a.y); o[2] = f2b(a.z); o[3] = f2b(a.w);
    o[4] = f2b(b.x); o[5] = f2b(b.y); o[6] = f2b(b.z); o[7] = f2b(b.w);
    ((u16x8*)d)[(size_t)off] = o;
}

// ---------------------------------------------------------------------------
// NT GEMM, bf16 in / fp32 acc. 128x64 tile, BK=64 as two BK=32 panels.
// VFUSE (QKV GEMM only): blocks with bn >= 2560 (V columns) write their
// C-tile transposed into Vt[col-2560][row]. Blocks with bid >= ngemm are
// wo->bf16 conversion blocks (overlapped with the GEMM).
// ---------------------------------------------------------------------------
template <bool OUT_BF16, bool QSCALE, bool VFUSE>
__global__ __launch_bounds__(256) void gemm_nt64(
    const u16* __restrict__ A, const u16* __restrict__ B,
    const float* __restrict__ bias, void* __restrict__ Cv,
    u16* __restrict__ Vt,
    const float* __restrict__ wosrc, u16* __restrict__ wodst,
    int N, int K, int nxb, int ngemm)
{
    __shared__ u16 As[2][128 * 32];
    __shared__ u16 Bs[2][64 * 32];
    const int bid = blockIdx.x;

    if (VFUSE && bid >= ngemm) {        // trailing wo-conversion blocks
        const int i = (bid - ngemm) * 256 + threadIdx.x;   // 0..524287
        const float4* s4 = (const float4*)wosrc;
        float4 a = s4[2 * (size_t)i], b = s4[2 * (size_t)i + 1];
        u16x8 o;
        o[0] = f2b(a.x); o[1] = f2b(a.y); o[2] = f2b(a.z); o[3] = f2b(a.w);
        o[4] = f2b(b.x); o[5] = f2b(b.y); o[6] = f2b(b.z); o[7] = f2b(b.w);
        ((u16x8*)wodst)[(size_t)i] = o;
        return;
    }

    const int wg  = (bid & 7) * (ngemm >> 3) + (bid >> 3);
    const int bm  = (wg / nxb) * 128;
    const int bn  = (wg % nxb) * 64;

    const int tid  = threadIdx.x;
    const int lane = tid & 63;
    const int w    = tid >> 6;
    const int wr   = w >> 1, wc = w & 1;
    const int la = lane & 15, lg = lane >> 4;

    f32x4 acc[4][2] = {};

    char* const abase = (char*)&As[0][0] + w * 1024;
    char* const bbase = (char*)&Bs[0][0] + w * 1024;

    for (int k0 = 0; k0 < K; k0 += 64) {
        #pragma unroll
        for (int i = 0; i < 4; ++i) {
            const int c   = tid + 256 * i;
            const int kh  = c >> 9;
            const int rem = c & 511;
            const int row = rem >> 2;
            const int seg = rem & 3;
            gld16(A + (size_t)(bm + row) * K + k0 + kh * 32 + seg * 8,
                  abase + i * 4096);
        }
        #pragma unroll
        for (int i = 0; i < 2; ++i) {
            const int c   = tid + 256 * i;
            const int kh  = c >> 8;
            const int rem = c & 255;
            const int row = rem >> 2;
            const int seg = rem & 3;
            gld16(B + (size_t)(bn + row) * K + k0 + kh * 32 + seg * 8,
                  bbase + i * 4096);
        }
        __syncthreads();
        #pragma unroll
        for (int kh = 0; kh < 2; ++kh) {
            bf16x8 af[4], bf[2];
            #pragma unroll
            for (int m = 0; m < 4; ++m)
                af[m] = *(const bf16x8*)(&As[kh][0] + (wr * 64 + m * 16 + la) * 32 + lg * 8);
            #pragma unroll
            for (int n = 0; n < 2; ++n)
                bf[n] = *(const bf16x8*)(&Bs[kh][0] + (wc * 32 + n * 16 + la) * 32 + lg * 8);
            #pragma unroll
            for (int m = 0; m < 4; ++m)
                #pragma unroll
                for (int n = 0; n < 2; ++n)
                    acc[m][n] = MFMA16(af[m], bf[n], acc[m][n]);
        }
        __syncthreads();
    }

    if (VFUSE && bn >= 2560) {
        // V columns: write transposed into Vt only.
        #pragma unroll
        for (int m = 0; m < 4; ++m) {
            #pragma unroll
            for (int n = 0; n < 2; ++n) {
                const int col = bn + wc * 32 + n * 16 + la;   // 2560..3071
                const float bb = bias[col];
                u16x4 pk;
                #pragma unroll
                for (int j = 0; j < 4; ++j)
                    pk[j] = f2b(acc[m][n][j] + bb);
                const int row0 = bm + wr * 64 + m * 16 + lg * 4;
                *(u16x4*)&Vt[(size_t)(col - 2560) * S_LEN + row0] = pk;
            }
        }
        return;
    }

    #pragma unroll
    for (int m = 0; m < 4; ++m) {
        #pragma unroll
        for (int n = 0; n < 2; ++n) {
            const int col = bn + wc * 32 + n * 16 + la;
            const float bb = bias[col];
            const float osc = (QSCALE && col < 2048) ? 0.180336881f : 1.0f;
            #pragma unroll
            for (int j = 0; j < 4; ++j) {
                const int row = bm + wr * 64 + m * 16 + lg * 4 + j;
                const float v = (acc[m][n][j] + bb) * osc;
                if (OUT_BF16) ((u16*)Cv)[(size_t)row * N + col] = f2b(v);
                else          ((float*)Cv)[(size_t)row * N + col] = v;
            }
        }
    }
}

// ---------------------------------------------------------------------------
// Flash attention v15 (= v13). Block = (32-row band, kv-head), 8 waves =
// 4 q-heads x 2 key-parities. Chunk pairs staged into dbuf LDS (XOR-swizzled
// source); K staged in-place from QKVb, V from Vt. permlane32_swap exchanges.
// LSE merge via aliased LDS. Complementary block pairing.
// ---------------------------------------------------------------------------
__global__ __launch_bounds__(512, 4) void attn(
    const u16* __restrict__ QKVb, // [2048][3072], Q cols pre-scaled
    const u16* __restrict__ Vt,   // [8][64][2048]
    u16* __restrict__ Ob)         // [2048][2048] bf16
{
    const int tid  = threadIdx.x;
    const int lane = tid & 63;
    const int w    = tid >> 6;           // 0..7
    const int head = w & 3;
    const int par  = w >> 2;             // key parity
    const int bid  = blockIdx.x;
    const int band = (bid < 256) ? (63 - (bid >> 3)) : ((bid - 256) >> 3);
    const int h    = bid & 7;
    const int hq   = h * 4 + head;
    const int q0   = band * 32;
    const int lq   = lane & 31;
    const int hi   = lane >> 5;

    __shared__ char LDS[65536];

    bf16x8 qf[4];
    #pragma unroll
    for (int ds = 0; ds < 4; ++ds)
        qf[ds] = *(const bf16x8*)&QKVb[(size_t)(q0 + lq) * QKVW + hq * 64 + ds * 16 + hi * 8];

    f32x16 ot[2] = {};
    float m = -3e38f, lsum = 0.f;

    const char* Khb = (const char*)QKVb + 4096 + h * 128;
    const char* Vhb = (const char*)(Vt + (size_t)h * 64 * S_LEN);

    const int r0 = tid >> 3;
    const int s0 = (((tid & 7) ^ (r0 & 7)) << 4);
    const int woff = w * 1024;

    const int nch = (band >> 1) + 1;
    const int nit = (nch + 1) >> 1;

    auto stage_pair = [&](int j) {
        const int pb = (j & 1) * 16384;
        const size_t kr = (size_t)(j * 128 + r0);
        gld16(Khb + kr * 6144 + s0,          LDS + pb + woff);
        gld16(Khb + (kr + 64) * 6144 + s0,   LDS + pb + 8192 + woff);
        const size_t vb = ((size_t)r0 << 12) + (size_t)(j * 256) + s0;
        gld16(Vhb + vb,        LDS + 32768 + pb + woff);
        gld16(Vhb + vb + 128,  LDS + 32768 + pb + 8192 + woff);
    };

    stage_pair(0);
    __syncthreads();

    for (int i = 0; i < nit; ++i) {
        if (i + 1 < nit) stage_pair(i + 1);

        const int cg = 2 * i + par;
        if (cg < nch) {
            const int base = (i & 1) * 16384 + par * 8192;
            const char* Kb = LDS + base;
            const char* Vb = LDS + 32768 + base;
            const int k0 = cg * 64;

            // ---- QK^T (swapped): S^T[key][q], exp2 domain
            f32x16 s[2];
            __builtin_amdgcn_s_setprio(1);
            #pragma unroll
            for (int kt = 0; kt < 2; ++kt) {
                f32x16 acc = {};
                #pragma unroll
                for (int ds = 0; ds < 4; ++ds) {
                    const int key = kt * 32 + lq;
                    const int byteK = (key << 7) + ((ds * 32 + hi * 16) ^ ((key & 7) << 4));
                    bf16x8 kf = *(const bf16x8*)(Kb + byteK);
                    acc = MFMA32(kf, qf[ds], acc);
                }
                s[kt] = acc;
            }
            __builtin_amdgcn_s_setprio(0);

            if (k0 + 63 > q0) {
                #pragma unroll
                for (int kt = 0; kt < 2; ++kt)
                    #pragma unroll
                    for (int r = 0; r < 16; ++r) {
                        const int key = k0 + kt * 32 + (r & 3) + 8 * (r >> 2) + 4 * hi;
                        if (key > q0 + lq) s[kt][r] = -1e30f;
                    }
            }

            // ---- chunk max: v_max3 tree + permlane cross-half
            float t10[11];
            #pragma unroll
            for (int r = 0; r < 10; ++r)
                t10[r] = max3f(s[(3*r) >> 4][(3*r) & 15],
                               s[(3*r+1) >> 4][(3*r+1) & 15],
                               s[(3*r+2) >> 4][(3*r+2) & 15]);
            t10[10] = fmaxf(s[1][14], s[1][15]);
            const float x0 = max3f(t10[0], t10[1], t10[2]);
            const float x1 = max3f(t10[3], t10[4], t10[5]);
            const float x2 = max3f(t10[6], t10[7], t10[8]);
            const float x3 = fmaxf(t10[9], t10[10]);
            const float pm = xhalf_max(fmaxf(max3f(x0, x1, x2), x3));

            // ---- defer-max rescale (exp2 domain, THR = 8*log2e)
            if (!__all(pm <= m + 11.5f)) {
                const float mn   = fmaxf(m, pm);
                const float corr = __builtin_exp2f(m - mn);
                m = mn;
                lsum *= corr;
                #pragma unroll
                for (int r = 0; r < 16; ++r) {
                    const int row = (r & 3) + 8 * (r >> 2) + 4 * hi;
                    const float cr = __shfl(corr, row);
                    ot[0][r] *= cr;
                    ot[1][r] *= cr;
                }
            }

            // ---- P = exp2(S - m); row sum via depth-5 tree
            #pragma unroll
            for (int kt = 0; kt < 2; ++kt)
                #pragma unroll
                for (int r = 0; r < 16; ++r)
                    s[kt][r] = __builtin_exp2f(s[kt][r] - m);
            float tsum[16];
            #pragma unroll
            for (int r = 0; r < 16; ++r) tsum[r] = s[0][r] + s[1][r];
            #pragma unroll
            for (int st = 8; st >= 1; st >>= 1)
                #pragma unroll
                for (int r = 0; r < 8; ++r)
                    if (r < st) tsum[r] += tsum[r + st];
            lsum += xhalf_sum(tsum[0]);

            // ---- pack P -> 4 PV A-frags (2 permlane swaps per kb)
            bf16x8 pa[4];
            #pragma unroll
            for (int kb = 0; kb < 4; ++kb) {
                const int kt = kb >> 1;
                const int rb = (kb & 1) * 8;
                const u32 A = pk2(s[kt][rb + 0], s[kt][rb + 1]);
                const u32 B = pk2(s[kt][rb + 4], s[kt][rb + 5]);
                const u32 C = pk2(s[kt][rb + 2], s[kt][rb + 3]);
                const u32 D = pk2(s[kt][rb + 6], s[kt][rb + 7]);
                u32 e0, e1, e2, e3;
                xswap(A, B, e0, e2);
                xswap(C, D, e1, e3);
                u32x4 t4;
                t4[0] = e0; t4[1] = e1; t4[2] = e2; t4[3] = e3;
                pa[kb] = __builtin_bit_cast(bf16x8, t4);
            }

            // ---- PV: U += P @ V
            __builtin_amdgcn_s_setprio(1);
            #pragma unroll
            for (int dt = 0; dt < 2; ++dt)
                #pragma unroll
                for (int kb = 0; kb < 4; ++kb) {
                    const int d = dt * 32 + lq;
                    const int byteV = (d << 7) + ((kb * 32 + hi * 16) ^ ((d & 7) << 4));
                    bf16x8 vf = *(const bf16x8*)(Vb + byteV);
                    ot[dt] = MFMA32(pa[kb], vf, ot[dt]);
                }
            __builtin_amdgcn_s_setprio(0);
        }

        __syncthreads();
    }

    // ---- split-K LSE merge via aliased LDS
    float* Uls = (float*)LDS;                    // [4][32][64]
    float* Mls = (float*)(LDS + 32768);          // [4][32]
    float* Lls = (float*)(LDS + 33280);          // [4][32]

    if (par == 1) {
        #pragma unroll
        for (int r = 0; r < 16; ++r) {
            const int row = (r & 3) + 8 * (r >> 2) + 4 * hi;
            Uls[(head * 32 + row) * 64 + lq]      = ot[0][r];
            Uls[(head * 32 + row) * 64 + 32 + lq] = ot[1][r];
        }
        if (lane < 32) { Mls[head * 32 + lane] = m; Lls[head * 32 + lane] = lsum; }
    }
    __syncthreads();
    if (par == 1) return;

    const float m1  = Mls[head * 32 + lq];
    const float l1  = Lls[head * 32 + lq];
    const float M   = fmaxf(m, m1);
    const float a0  = __builtin_exp2f(m - M);
    const float a1  = __builtin_exp2f(m1 - M);
    const float inv = 1.f / (a0 * lsum + a1 * l1);

    #pragma unroll
    for (int r = 0; r < 16; ++r) {
        const int row = (r & 3) + 8 * (r >> 2) + 4 * hi;
        const float a0r = __shfl(a0, row);
        const float a1r = __shfl(a1, row);
        const float ivr = __shfl(inv, row);
        #pragma unroll
        for (int dt = 0; dt < 2; ++dt) {
            const float u1 = Uls[(head * 32 + row) * 64 + dt * 32 + lq];
            Ob[(size_t)(q0 + row) * DM + hq * 64 + dt * 32 + lq] =
                f2b((a0r * ot[dt][r] + a1r * u1) * ivr);
        }
    }
}

// ---------------------------------------------------------------------------
extern "C" void kernel_launch(void* const* d_in, const int* in_sizes, int n_in,
                              void* d_out, int out_size, void* d_ws, size_t ws_size,
                              hipStream_t stream)
{
    const float* x  = (const float*)d_in[0];
    const float* wq = (const float*)d_in[1];
    const float* bq = (const float*)d_in[2];
    const float* wk = (const float*)d_in[3];
    const float* bk = (const float*)d_in[4];
    const float* wv = (const float*)d_in[5];
    const float* bv = (const float*)d_in[6];
    const float* wo = (const float*)d_in[7];
    const float* bo = (const float*)d_in[8];
    float* out = (float*)d_out;

    char* ws = (char*)d_ws;
    u16* xb     = (u16*)(ws);                  // 8 MB; dead after QKV GEMM
    u16* wqkvb  = (u16*)(ws + (8u  << 20));    // 12 MB; dead after QKV GEMM
    u16* wob    = (u16*)(ws + (20u << 20));    // 8 MB
    u16* QKVb   = (u16*)(ws + (28u << 20));    // 12 MB
    float* bqkv = (float*)(ws + (40u << 20));  // 12 KB
    u16* Ob = xb;                              // 8 MB (aliases dead xb)
    u16* Vt = (u16*)(ws + (41u << 20));        // 2 MB

    cvt5<<<5121, 256, 0, stream>>>(x, wq, wk, wv, bq, bk, bv, xb, wqkvb, bqkv);
    // 768 GEMM blocks + 2048 trailing wo-cvt blocks (overlapped)
    gemm_nt64<true, true, true><<<768 + 2048, 256, 0, stream>>>(
        xb, wqkvb, bqkv, QKVb, Vt, wo, wob, QKVW, 2048, QKVW / 64, 768);
    attn<<<512, 512, 0, stream>>>(QKVb, Vt, Ob);
    gemm_nt64<false, false, false><<<512, 256, 0, stream>>>(
        Ob, wob, bo, out, nullptr, nullptr, nullptr, DM, 2048, DM / 64, 512);
}